// Round 5
// baseline (435.015 us; speedup 1.0000x reference)
//
#include <hip/hip_runtime.h>
#include <math.h>

// Problem constants (fixed by the reference):
// B=2, N=131072 (=2^17), K=9, P=4, D=4, S=1, CI=8, CO=8
#define N_PTS 131072
#define KNB   9
#define PD    16          // P*D*S = 16 (p,d) cells per point
#define CIN   8
#define COUT  8
#define THREADS 256       // ONE POINT PER THREAD: thread owns all 16 pd cells

// Native clang vectors (NOT HIP_vector_type) — required by nontemporal builtins,
// and f32x2/f32x4 arithmetic maps to v_pk_fma_f32 (2 fp32 FMA / instr).
typedef float f32x2 __attribute__((ext_vector_type(2)));
typedef float f32x4 __attribute__((ext_vector_type(4)));
typedef int   i32x4 __attribute__((ext_vector_type(4)));

#if __has_builtin(__builtin_amdgcn_exp2f)
#define EXP2F(v) __builtin_amdgcn_exp2f(v)
#else
#define EXP2F(v) exp2f(v)
#endif

__global__ __launch_bounds__(THREADS) void polnormal_kernel(
    const float* __restrict__ x,      // (B, N, CI)
    const float* __restrict__ dx,     // (B, N, K)
    const float* __restrict__ dy,     // (B, N, K)
    const int*   __restrict__ adj,    // (N, K)
    const float* __restrict__ phis,  // (P,)
    const float* __restrict__ dists, // (D,)
    const float* __restrict__ sigma, // (S,) = (1,)
    const float* __restrict__ amp,   // (P, D, S, CI, CO) = (pd, c, o)
    float*       __restrict__ out)   // (B, N, P, D, S, CO)
{
    // Thread-per-point: per-point data (x rows, dd) is read ONCE per point
    // (was 16x redundant LDS traffic in the (point x pd) decomposition);
    // per-pd data (amp, mu-constants) becomes wave-uniform -> LDS broadcast.
    __shared__ float s_dd[THREADS * KNB * 2];   // interleaved (dx,dy)  18.0 KB
    __shared__ int   s_adj[THREADS * KNB];      //                       9.0 KB
    __shared__ float s_amp[PD * CIN * COUT];    // flat [pd][c][o]       4.0 KB
    __shared__ f32x2 s_t12[PD];                 // (-2*c1*mux, -2*c1*muy)
    __shared__ float s_rr[PD];                  // c1*(mux^2+muy^2)
    __shared__ float s_c[2];                    // c1, c2

    const int  tid    = threadIdx.x;
    const long base_g = (long)blockIdx.x * THREADS;   // flattened (b,n); 256 | N
    const int  b      = (int)(base_g >> 17);          // N = 2^17
    const int  base_n = (int)(base_g & (N_PTS - 1));

    // --- Staging (one barrier) ---

    // dx/dy: 2304 floats each = 576 f32x4, NON-TEMPORAL (stream-once; keep L2
    // for x). Interleaved into s_dd so compute does one ds_read_b64 per k.
    // Flat local float index f -> s_dd[2f] = dx, s_dd[2f+1] = dy.
    for (int t = tid; t < 2 * 576; t += THREADS) {
        if (t < 576) {
            f32x4 v = __builtin_nontemporal_load(&((const f32x4*)dx)[(long)blockIdx.x * 576 + t]);
#pragma unroll
            for (int j = 0; j < 4; ++j) s_dd[(4 * t + j) * 2] = v[j];
        } else {
            const int u = t - 576;
            f32x4 v = __builtin_nontemporal_load(&((const f32x4*)dy)[(long)blockIdx.x * 576 + u]);
#pragma unroll
            for (int j = 0; j < 4; ++j) s_dd[(4 * u + j) * 2 + 1] = v[j];
        }
    }
    // adj: 2304 ints = 576 int4, NON-TEMPORAL. base_n*9 is a multiple of 2304 -> aligned.
    for (int t = tid; t < 576; t += THREADS) {
        ((i32x4*)s_adj)[t] =
            __builtin_nontemporal_load(&((const i32x4*)adj)[((long)base_n * KNB) / 4 + t]);
    }
    // Amplitudes: 4 KB flat; all compute reads are wave-uniform (broadcast).
    ((f32x4*)s_amp)[tid] = ((const f32x4*)amp)[tid];

    // Per-pd constants (16 values) + sigma constants, computed once per block.
    if (tid < PD) {
        const float sig = fmaxf(sigma[0], 1e-10f);
        const float s2  = sig * sig;
        const float c1  = (-0.5f / s2) * 1.44269504088896340736f;  // log2 e
        const int p = tid >> 2, d = tid & 3;
        float sn, cs;
        __sincosf(phis[p], &sn, &cs);
        const float dist = dists[d];
        const float mux = cs * dist, muy = sn * dist;
        s_t12[tid] = (f32x2){ -2.0f * c1 * mux, -2.0f * c1 * muy };
        s_rr[tid]  = c1 * (mux * mux + muy * muy);
        if (tid == 0) {
            s_c[0] = c1;
            s_c[1] = -0.5f * __log2f(6.283185307179586f * s2);   // log2(norm)
        }
    }
    __syncthreads();

    // --- Compute: this thread owns point (b, base_n + tid) ---

    // dd in registers: 9 x ds_read_b64 (8B-aligned: (tid*9+k)*8 bytes).
    f32x2 dd[KNB];
#pragma unroll
    for (int k = 0; k < KNB; ++k) dd[k] = *(const f32x2*)&s_dd[(tid * KNB + k) * 2];

    // Gather x rows into registers (issued early; L2-resident since all
    // streaming traffic is nontemporal). 18 independent dwordx4 loads.
    f32x4 xr[KNB][2];
#pragma unroll
    for (int k = 0; k < KNB; ++k) {
        const long row = (long)s_adj[tid * KNB + k];
        const f32x4* src = (const f32x4*)(x + (((long)b << 17) + row) * CIN);
        xr[k][0] = src[0];
        xr[k][1] = src[1];
    }

    // A[k] = c1*(dx^2+dy^2) + c2  (pd-independent part of the exponent;
    // r2 expanded: arg = A[k] + rr[pd] + t1[pd]*dx + t2[pd]*dy).
    const float c1 = s_c[0], c2 = s_c[1];
    float A[KNB];
#pragma unroll
    for (int k = 0; k < KNB; ++k) {
        const float q = fmaf(dd[k].x, dd[k].x, dd[k].y * dd[k].y);
        A[k] = fmaf(q, c1, c2);
    }

    float* op = out + (long)(base_g + tid) * (PD * COUT);   // 512 B contiguous/thread

    for (int pd = 0; pd < PD; ++pd) {      // rolled loop: ~140-instr body
        const f32x2 t12 = s_t12[pd];       // LDS broadcast
        const float rr  = s_rr[pd];

        f32x4 wx0 = (f32x4)(0.0f), wx1 = (f32x4)(0.0f);
#pragma unroll
        for (int k = 0; k < KNB; ++k) {
            const float arg = fmaf(t12.x, dd[k].x, fmaf(t12.y, dd[k].y, A[k] + rr));
            const float w   = EXP2F(arg);
            const f32x4 wv  = (f32x4)(w);
            wx0 += wv * xr[k][0];          // packed fma
            wx1 += wv * xr[k][1];
        }

        // Matvec: amp rows are wave-uniform LDS reads (broadcast, conflict-free).
        f32x4 acc0 = (f32x4)(0.0f), acc1 = (f32x4)(0.0f);
        const f32x4* arow = (const f32x4*)&s_amp[pd * (CIN * COUT)];
#pragma unroll
        for (int c = 0; c < CIN; ++c) {
            const float wc  = (c < 4) ? wx0[c] : wx1[c - 4];
            const f32x4 wcv = (f32x4)(wc);
            acc0 += wcv * arow[c * 2];
            acc1 += wcv * arow[c * 2 + 1];
        }

        // 64 B per pd, thread-contiguous; wave writes 32 KB contiguous. NT stream.
        __builtin_nontemporal_store(acc0, (f32x4*)(op + pd * 8));
        __builtin_nontemporal_store(acc1, (f32x4*)(op + pd * 8 + 4));
    }
}

extern "C" void kernel_launch(void* const* d_in, const int* in_sizes, int n_in,
                              void* d_out, int out_size, void* d_ws, size_t ws_size,
                              hipStream_t stream) {
    const float* x     = (const float*)d_in[0];
    const float* dx    = (const float*)d_in[1];
    const float* dy    = (const float*)d_in[2];
    const int*   adj   = (const int*)  d_in[3];
    const float* phis  = (const float*)d_in[4];
    const float* dists = (const float*)d_in[5];
    const float* sigma = (const float*)d_in[6];
    const float* amp   = (const float*)d_in[7];
    float* out = (float*)d_out;

    const int total_pts = 2 * N_PTS;                 // B*N = 262144
    const int grid = total_pts / THREADS;            // 1024 blocks, 4/CU exact
    polnormal_kernel<<<grid, THREADS, 0, stream>>>(x, dx, dy, adj, phis, dists,
                                                   sigma, amp, out);
}

// Round 6
// 198.785 us; speedup vs baseline: 2.1884x; 2.1884x over previous
//
#include <hip/hip_runtime.h>
#include <math.h>

// Problem constants (fixed by the reference):
// B=2, N=131072 (=2^17), K=9, P=4, D=4, S=1, CI=8, CO=8
#define N_PTS 131072
#define KNB   9
#define PD    16
#define CIN   8
#define COUT  8
#define THREADS 256       // one point per thread; 4 waves/block
#define WAVES   4
#define POOLF   1728      // floats per wave pool: 576 ddx | 576 ddy | 576 adj(int)

// Native clang vectors (required by nontemporal builtins; map to packed fp32 math).
typedef float f32x2 __attribute__((ext_vector_type(2)));
typedef float f32x4 __attribute__((ext_vector_type(4)));
typedef int   i32x4 __attribute__((ext_vector_type(4)));

#if __has_builtin(__builtin_amdgcn_exp2f)
#define EXP2F(v) __builtin_amdgcn_exp2f(v)
#else
#define EXP2F(v) exp2f(v)
#endif

__global__ __launch_bounds__(THREADS) void polnormal_kernel(
    const float* __restrict__ x,      // (B, N, CI)
    const float* __restrict__ dx,     // (B, N, K)
    const float* __restrict__ dy,     // (B, N, K)
    const int*   __restrict__ adj,    // (N, K)
    const float* __restrict__ phis,  // (P,)
    const float* __restrict__ dists, // (D,)
    const float* __restrict__ sigma, // (S,) = (1,)
    const float* __restrict__ amp,   // (P, D, S, CI, CO) = (pd, c, o)
    float*       __restrict__ out)   // (B, N, P, D, S, CO)
{
    // Per-wave pool: staging for ddx/ddy/adj of the wave's 64 points; after
    // those are consumed into registers, the SAME region is reused as the
    // wave-private output-transpose buffer (64 pts * 20 floats = 1280 < 1728).
    // Wave-private reuse => no __syncthreads after the initial one.
    __shared__ float s_pool[WAVES * POOLF];     // 27648 B
    __shared__ float s_amp[PD * CIN * COUT];    //  4096 B, [pd][c][o]
    __shared__ f32x2 s_t12[PD];                 // (-2*c1*mux, -2*c1*muy)
    __shared__ float s_rr[PD];                  // c1*(mux^2+muy^2)
    __shared__ float s_c[2];                    // c1, c2

    const int  tid    = threadIdx.x;
    const long base_g = (long)blockIdx.x * THREADS;   // flattened (b,n); 256 | N
    const int  b      = (int)(base_g >> 17);          // N = 2^17
    const int  base_n = (int)(base_g & (N_PTS - 1));

    // --- Staging (single barrier) ---
    // dx/dy/adj are stream-once -> NONTEMPORAL (keep L2 for the reused x).
    // Flat pair index f = pt*9+k; wave w owns f in [w*576,(w+1)*576).
    for (int t = tid; t < 576; t += THREADS) {
        f32x4 vx = __builtin_nontemporal_load(&((const f32x4*)dx)[(long)blockIdx.x * 576 + t]);
        f32x4 vy = __builtin_nontemporal_load(&((const f32x4*)dy)[(long)blockIdx.x * 576 + t]);
        i32x4 va = __builtin_nontemporal_load(&((const i32x4*)adj)[((long)base_n * KNB) / 4 + t]);
        const int w   = (4 * t) / 576;       // 4|576 -> all 4 elems same wave pool
        const int idx = (4 * t) % 576;
        *(f32x4*)&s_pool[w * POOLF + idx]        = vx;
        *(f32x4*)&s_pool[w * POOLF + 576 + idx]  = vy;
        *(i32x4*)&s_pool[w * POOLF + 1152 + idx] = va;
    }
    // Amplitudes: 4 KB; all compute reads are wave-uniform (LDS broadcast).
    ((f32x4*)s_amp)[tid] = ((const f32x4*)amp)[tid];

    // Per-pd constants, computed once per block.
    if (tid < PD) {
        const float sig = fmaxf(sigma[0], 1e-10f);
        const float s2  = sig * sig;
        const float c1  = (-0.5f / s2) * 1.44269504088896340736f;  // log2 e
        const int p = tid >> 2, d = tid & 3;
        float sn, cs;
        __sincosf(phis[p], &sn, &cs);
        const float dist = dists[d];
        const float mux = cs * dist, muy = sn * dist;
        s_t12[tid] = (f32x2){ -2.0f * c1 * mux, -2.0f * c1 * muy };
        s_rr[tid]  = c1 * (mux * mux + muy * muy);
        if (tid == 0) {
            s_c[0] = c1;
            s_c[1] = -0.5f * __log2f(6.283185307179586f * s2);   // log2(norm)
        }
    }
    __syncthreads();

    // --- Compute: this thread owns point (b, base_n + tid) ---
    const int w = tid >> 6;          // wave id
    const int l = tid & 63;          // lane
    float* poolw = &s_pool[w * POOLF];

    // dd + adj into registers (conflict-free b32: lane stride 9 elems, 9 odd).
    float ddxv[KNB], ddyv[KNB];
    int   rows[KNB];
#pragma unroll
    for (int k = 0; k < KNB; ++k) {
        ddxv[k] = poolw[l * KNB + k];
        ddyv[k] = poolw[576 + l * KNB + k];
        rows[k] = ((const int*)poolw)[1152 + l * KNB + k];
    }

    // Gather x rows into registers (18 loads, L2-resident since all streaming
    // traffic is nontemporal). Issued early; consumed across the chunk loop.
    f32x4 xr[KNB][2];
#pragma unroll
    for (int k = 0; k < KNB; ++k) {
        const f32x4* src = (const f32x4*)(x + (((long)b << 17) + rows[k]) * CIN);
        xr[k][0] = src[0];
        xr[k][1] = src[1];
    }

    // A[k] = c1*(ddx^2+ddy^2) + c2 (pd-independent exponent part);
    // full arg = A[k] + rr[pd] + t1[pd]*ddx + t2[pd]*ddy.
    const float c1 = s_c[0], c2 = s_c[1];
    float Ak[KNB];
#pragma unroll
    for (int k = 0; k < KNB; ++k) {
        const float q = fmaf(ddxv[k], ddxv[k], ddyv[k] * ddyv[k]);
        Ak[k] = fmaf(q, c1, c2);
    }

    // Output in 8 chunks of 2 pd cells, transposed through wave-private LDS so
    // every global store instruction writes 16 FULL 64B lines back-to-back
    // (R5 wrote 32B half-lines spread 140 instrs apart -> NT partial-line
    // eviction -> 2.5x write amplification; this is the fix).
    float* bufw = poolw;             // reuse: 64 pts * 20 floats (80B stride)
    const int pt_l = l >> 2;         // store phase: 4 lanes per point
    const int u    = l & 3;

    for (int c = 0; c < 8; ++c) {
        f32x4 accq[4];               // 2 pd * (2 quads of 4 outputs)
#pragma unroll
        for (int h = 0; h < 2; ++h) {
            const int pdc = 2 * c + h;
            const f32x2 t12 = s_t12[pdc];      // wave-uniform broadcast
            const float rr  = s_rr[pdc];

            f32x4 wx0 = (f32x4)(0.0f), wx1 = (f32x4)(0.0f);
#pragma unroll
            for (int k = 0; k < KNB; ++k) {
                const float arg = fmaf(t12.x, ddxv[k], fmaf(t12.y, ddyv[k], Ak[k] + rr));
                const float wgt = EXP2F(arg);
                const f32x4 wv  = (f32x4)(wgt);
                wx0 += wv * xr[k][0];          // packed fma
                wx1 += wv * xr[k][1];
            }

            f32x4 acc0 = (f32x4)(0.0f), acc1 = (f32x4)(0.0f);
            const f32x4* arow = (const f32x4*)&s_amp[pdc * (CIN * COUT)];
#pragma unroll
            for (int cc = 0; cc < CIN; ++cc) {
                const float wc  = (cc < 4) ? wx0[cc] : wx1[cc - 4];
                const f32x4 wcv = (f32x4)(wc);
                acc0 += wcv * arow[cc * 2];
                acc1 += wcv * arow[cc * 2 + 1];
            }
            accq[2 * h]     = acc0;
            accq[2 * h + 1] = acc1;
        }

        // Wave-private transpose. lgkmcnt(0) fences: (a) prior chunk's buf
        // reads done before overwrite, (b) writes visible before readback.
        asm volatile("s_waitcnt lgkmcnt(0)" ::: "memory");
#pragma unroll
        for (int q = 0; q < 4; ++q)
            *(f32x4*)&bufw[l * 20 + q * 4] = accq[q];
        asm volatile("s_waitcnt lgkmcnt(0)" ::: "memory");
        __builtin_amdgcn_sched_barrier(0);

        // Coalesced NT stores: lane (pt_l,u), 4 groups -> 64 pts * 64 B chunk.
        // buf[pt*20 + u*4] = point pt, floats [pd=2c..2c+1][o] -> global
        // float offset (base+pt)*128 + c*16 + u*4.
#pragma unroll
        for (int g = 0; g < 4; ++g) {
            const int pt = pt_l + 16 * g;
            const f32x4 v = *(const f32x4*)&bufw[pt * 20 + u * 4];
            float* dst = out + ((long)(base_g + w * 64 + pt)) * (PD * COUT) + c * 16 + u * 4;
            __builtin_nontemporal_store(v, (f32x4*)dst);
        }
    }
}

extern "C" void kernel_launch(void* const* d_in, const int* in_sizes, int n_in,
                              void* d_out, int out_size, void* d_ws, size_t ws_size,
                              hipStream_t stream) {
    const float* x     = (const float*)d_in[0];
    const float* dx    = (const float*)d_in[1];
    const float* dy    = (const float*)d_in[2];
    const int*   adj   = (const int*)  d_in[3];
    const float* phis  = (const float*)d_in[4];
    const float* dists = (const float*)d_in[5];
    const float* sigma = (const float*)d_in[6];
    const float* amp   = (const float*)d_in[7];
    float* out = (float*)d_out;

    const int total_pts = 2 * N_PTS;                 // B*N = 262144
    const int grid = total_pts / THREADS;            // 1024 blocks
    polnormal_kernel<<<grid, THREADS, 0, stream>>>(x, dx, dy, adj, phis, dists,
                                                   sigma, amp, out);
}